// Round 5
// baseline (331.250 us; speedup 1.0000x reference)
//
#include <hip/hip_runtime.h>
#include <hip/hip_bf16.h>

typedef __bf16 bf16x8 __attribute__((ext_vector_type(8)));
typedef __bf16 bf16x4 __attribute__((ext_vector_type(4)));
typedef float  f32x4  __attribute__((ext_vector_type(4)));

#define NTOK 16384
#define DDIM 1024
#define HDIM 1024

// workspace layout (bytes)
#define XB_OFF   0u          // bf16 x        [NTOK][DDIM]     33,554,432
#define WT_OFF   33554432u   // bf16 W^T      [E][H][D]        16,777,216
#define IDXP_OFF 50331648u   // int   idx_packed [NTOK]            65,536
#define PPP_OFF  50397184u   // f32x2 pp_packed  [NTOK]           131,072
#define TPID_OFF 50528256u   // int   tt_pid [NTOK]                65,536
#define TPP_OFF  50593792u   // f32x2 tt_pp  [NTOK]               131,072
#define CNTB_OFF 50724864u   // u8  cnt_blk [1024][64]             65,536
#define ENTB_OFF 50790400u   // f32 ent_blk [1024]                  4,096
#define TOT_OFF  50794496u   // int tot [64]                          256

typedef __attribute__((address_space(1))) void gvoid_t;
typedef __attribute__((address_space(3))) void lvoid_t;

__device__ __forceinline__ void cp16(void* lds, const void* g) {
  __builtin_amdgcn_global_load_lds((gvoid_t*)g, (lvoid_t*)lds, 16, 0, 0);
}

// ============ K1: fused  transpose_w (blocks 0..2047)  +  gate (2048..3071) ====
// One dispatch instead of two (independent producers). Gate emits PER-BLOCK
// count bytes + per-block entropy with plain stores -> no zeroed global memory
// anywhere in the pipeline, no global atomics.
__global__ __launch_bounds__(256) void prep_kernel(
    const float* __restrict__ ew, __bf16* __restrict__ wT,
    const float* __restrict__ x, const float* __restrict__ gw,
    const float* __restrict__ gb, __bf16* __restrict__ xb,
    int* __restrict__ tt_pid, float2* __restrict__ tt_pp,
    unsigned char* __restrict__ cnt_blk, float* __restrict__ ent_blk) {
  __shared__ __align__(16) char smem[33040];
  const int tid = threadIdx.x;

  if (blockIdx.x < 2048) {
    // ---- transpose path: expert_w [E][D][H] f32 -> W^T [E][H][D] bf16 ----
    typedef float (*TileT)[69];
    TileT tile = (TileT)smem;
    const int b  = blockIdx.x;
    const int e  = b >> 8;
    const int d0 = ((b >> 4) & 15) * 64;
    const int h0 = (b & 15) * 64;
    const float* base = ew + ((size_t)e * DDIM + d0) * HDIM + h0;
#pragma unroll
    for (int it = 0; it < 4; ++it) {
      int dl = it * 16 + (tid >> 4);
      int hl = (tid & 15) * 4;
      float4 v = *(const float4*)(base + (size_t)dl * HDIM + hl);
      tile[dl][hl]     = v.x;
      tile[dl][hl + 1] = v.y;
      tile[dl][hl + 2] = v.z;
      tile[dl][hl + 3] = v.w;
    }
    __syncthreads();
    __bf16* obase = wT + ((size_t)e * HDIM + h0) * DDIM + d0;
#pragma unroll
    for (int it = 0; it < 2; ++it) {
      int hl = it * 32 + (tid >> 3);   // h row 0..63
      int dl = (tid & 7) * 8;          // 16B chunk of the 128B d-row
      bf16x8 bv;
#pragma unroll
      for (int i = 0; i < 8; ++i) bv[i] = (__bf16)tile[dl + i][hl];
      *(bf16x8*)(obase + (size_t)hl * DDIM + dl) = bv;
    }
    return;
  }

  // ---- gate path: logits/softmax/entropy/top2 -> pid+probs, x->bf16 ----
  float* gwT  = (float*)smem;            // 8*1024 f32 = 32768 B
  int*   lcnt = (int*)(smem + 32768);    // 64 ints
  float* went = (float*)(smem + 33024);  // 4 f32
  const int bid = blockIdx.x - 2048;
  const int wv = tid >> 6, lane = tid & 63;
  for (int i = tid; i < 64; i += 256) lcnt[i] = 0;
#pragma unroll
  for (int i = 0; i < 32; ++i) {  // gate_w [D][8] -> gwT [8][1024]
    int lin = i * 256 + tid;
    gwT[(lin & 7) * 1024 + (lin >> 3)] = gw[lin];
  }
  __syncthreads();
  float4 gr[4][8];
#pragma unroll
  for (int j = 0; j < 4; ++j)
#pragma unroll
    for (int e = 0; e < 8; ++e)
      gr[j][e] = *(const float4*)&gwT[e * 1024 + j * 256 + lane * 4];
  float gbr[8];
#pragma unroll
  for (int e = 0; e < 8; ++e) gbr[e] = gb[e];

  float entacc = 0.f;
  for (int t = 0; t < 4; ++t) {
    const int n = bid * 16 + wv * 4 + t;
    float acc[8] = {0.f, 0.f, 0.f, 0.f, 0.f, 0.f, 0.f, 0.f};
#pragma unroll
    for (int j = 0; j < 4; ++j) {
      float4 v = *(const float4*)(x + (size_t)n * DDIM + j * 256 + lane * 4);
      bf16x4 bv;
      bv[0] = (__bf16)v.x; bv[1] = (__bf16)v.y;
      bv[2] = (__bf16)v.z; bv[3] = (__bf16)v.w;
      *(bf16x4*)(xb + (size_t)n * DDIM + j * 256 + lane * 4) = bv;
#pragma unroll
      for (int e = 0; e < 8; ++e) {
        float4 g = gr[j][e];
        acc[e] += v.x * g.x + v.y * g.y + v.z * g.z + v.w * g.w;
      }
    }
#pragma unroll
    for (int e = 0; e < 8; ++e) {
      float s = acc[e];
#pragma unroll
      for (int off = 1; off < 64; off <<= 1) s += __shfl_xor(s, off);
      acc[e] = s;
    }
    // softmax + entropy via log-identity: ent = log(s) - sum p*(l-mx)
    float p[8], lg[8];
    float mx = -1e30f;
#pragma unroll
    for (int e = 0; e < 8; ++e) { p[e] = acc[e] + gbr[e]; mx = fmaxf(mx, p[e]); }
    float s = 0.f;
#pragma unroll
    for (int e = 0; e < 8; ++e) { lg[e] = p[e] - mx; p[e] = expf(lg[e]); s += p[e]; }
    float inv = 1.0f / s;
    float dot = 0.f;
#pragma unroll
    for (int e = 0; e < 8; ++e) { p[e] *= inv; dot += p[e] * lg[e]; }
    entacc += logf(s) - dot;
    int e1 = 0; float p1 = p[0];
#pragma unroll
    for (int e = 1; e < 8; ++e) if (p[e] > p1) { p1 = p[e]; e1 = e; }
    int e2 = (e1 == 0) ? 1 : 0; float p2 = p[e2];
#pragma unroll
    for (int e = 0; e < 8; ++e) if (e != e1 && p[e] > p2) { p2 = p[e]; e2 = e; }
    int   elo = (e1 < e2) ? e1 : e2;
    int   ehi = (e1 < e2) ? e2 : e1;
    float plo = (e1 < e2) ? p1 : p2;
    float phi = (e1 < e2) ? p2 : p1;
    int pid = elo * 8 + ehi;
    if (lane == 0) {
      tt_pid[n] = pid;
      tt_pp[n]  = make_float2(plo, phi);
      atomicAdd(&lcnt[pid], 1);
    }
  }
  if (lane == 0) went[wv] = entacc;
  __syncthreads();
  if (tid < 64) cnt_blk[bid * 64 + tid] = (unsigned char)lcnt[tid];
  if (tid == 0) ent_blk[bid] = went[0] + went[1] + went[2] + went[3];
}

// ============ K2: scatter (computes bases itself; block 0 does loss) ==========
// Replaces scan+scatter. Each block column-reduces cnt_blk[1024][64] into
// totals + its own cross-block offsets (deterministic, no global atomics).
// R5 FIX: scatter block b owns tokens from GATE blocks [16b,16b+16), so its
// cross-block offset must count gate blocks bb < 16*b (R4 compared bb < b ->
// overlapping dst -> corrupted idx_p -> wild gathers -> device fault).
__global__ __launch_bounds__(256) void scatter_kernel(
    const int* __restrict__ tt_pid, const float2* __restrict__ tt_pp,
    const unsigned char* __restrict__ cnt_blk, const float* __restrict__ ent_blk,
    int* __restrict__ idx_p, float2* __restrict__ pp_p,
    int* __restrict__ tot_g, float* __restrict__ loss_out) {
  __shared__ int part_tot[4][64], part_off[4][64];
  __shared__ int tot_l[64], off_l[64], base_l[64], lcnt[64];
  __shared__ float esum[4];
  const int t = threadIdx.x, b = blockIdx.x;
  const int p = t & 63, q = t >> 6;
  const int bcut = b * 16;   // first gate block owned by this scatter block

  int s_tot = 0, s_off = 0;
  for (int i = 0; i < 256; ++i) {
    int bb = q * 256 + i;
    int c = cnt_blk[bb * 64 + p];   // 64 lanes hit one 64B line per iter
    s_tot += c;
    s_off += (bb < bcut) ? c : 0;
  }
  part_tot[q][p] = s_tot;
  part_off[q][p] = s_off;
  if (t < 64) lcnt[t] = 0;
  __syncthreads();
  if (t < 64) {
    tot_l[t] = part_tot[0][t] + part_tot[1][t] + part_tot[2][t] + part_tot[3][t];
    off_l[t] = part_off[0][t] + part_off[1][t] + part_off[2][t] + part_off[3][t];
  }
  __syncthreads();
  if (t < 64) {
    int base = 0;
    for (int i = 0; i < t; ++i) base += tot_l[i];
    base_l[t] = base;
  }
  const int n   = b * 256 + t;
  const int pid = tt_pid[n];
  const float2 pp = tt_pp[n];
  __syncthreads();
  int lofs = atomicAdd(&lcnt[pid], 1);   // within-segment order arbitrary (ok)
  int dst = base_l[pid] + off_l[pid] + lofs;
  idx_p[dst] = n;
  pp_p[dst]  = pp;

  if (b == 0) {
    if (t < 64) tot_g[t] = tot_l[t];
    // entropy reduce: 1024 floats
    float e = ent_blk[t] + ent_blk[t + 256] + ent_blk[t + 512] + ent_blk[t + 768];
#pragma unroll
    for (int off = 1; off < 64; off <<= 1) e += __shfl_xor(e, off);
    if ((t & 63) == 0) esum[t >> 6] = e;
    __syncthreads();
    if (t == 0) {
      float ent = esum[0] + esum[1] + esum[2] + esum[3];
      int ecnt[8] = {0, 0, 0, 0, 0, 0, 0, 0};
      for (int pd = 0; pd < 64; ++pd) {
        int c = tot_l[pd];
        ecnt[pd >> 3] += c;
        ecnt[pd & 7]  += c;
      }
      float pen = 0.f;
      for (int e8 = 0; e8 < 8; ++e8) {
        float r = (float)ecnt[e8] / (float)NTOK - 0.3f;
        if (r > 0.f) pen += r;
      }
      loss_out[0] = 0.1f * (ent / (float)NTOK) + pen;
    }
  }
}

// ============ K3: pair-grouped dual-expert GEMM (R0-exact structure) ==========
// Identity (gy,gx) mapping -- R3 proved default dispatch gives each XCD an
// L2-resident 2MB weight slab (gx == XCD). Tile descriptor derived in-kernel
// from tot_g (64-iter thread-0 walk) -> scan dispatch eliminated.
__global__ __launch_bounds__(256) void moe_gemm(
    const __bf16* __restrict__ xb, const __bf16* __restrict__ wT,
    const float* __restrict__ eb, const int* __restrict__ idx_p,
    const float2* __restrict__ pp_p, const int* __restrict__ tot_g,
    float* __restrict__ out) {
  const int gy = blockIdx.y, gx = blockIdx.x;

  __shared__ __bf16 Ash[128 * 64];
  __shared__ __bf16 BloS[128 * 64];
  __shared__ __bf16 BhiS[128 * 64];
  __shared__ int    tok_s[128];
  __shared__ float2 pp_s[128];
  __shared__ int    tot_s[64];
  __shared__ int    hdr[4];

  const int tid = threadIdx.x, w = tid >> 6, lane = tid & 63;
  if (tid < 64) tot_s[tid] = tot_g[tid];
  __syncthreads();
  if (tid == 0) {
    int bacc = 0, ti = 0, fpid = -1, frow = 0, fcnt = 0, fbase = 0;
    for (int pd = 0; pd < 64; ++pd) {
      int c = tot_s[pd];
      if (c > 0) {
        int ntl = (c + 127) >> 7;
        if (gy >= ti && gy < ti + ntl) {
          fpid = pd; frow = (gy - ti) * 128; fcnt = c; fbase = bacc;
        }
        ti += ntl;
        bacc += c;
      }
    }
    hdr[0] = fpid; hdr[1] = frow; hdr[2] = fcnt; hdr[3] = fbase;
  }
  __syncthreads();
  const int pid = hdr[0];
  if (pid < 0) return;
  const int row0 = hdr[1], cntp = hdr[2], gbase = hdr[3];
  const int elo = pid >> 3, ehi = pid & 7;

  if (tid < 128) {
    int s = row0 + tid;
    int g = gbase + ((s < cntp) ? s : (cntp - 1));
    tok_s[tid] = idx_p[g];
    pp_s[tid]  = pp_p[g];
  }
  __syncthreads();

  f32x4 accL[4][4], accH[4][4];
  const f32x4 zero = {0.f, 0.f, 0.f, 0.f};
#pragma unroll
  for (int mi = 0; mi < 4; ++mi)
#pragma unroll
    for (int ni = 0; ni < 4; ++ni) { accL[mi][ni] = zero; accH[mi][ni] = zero; }

  const int wm = (w >> 1) * 64, wn = (w & 1) * 64;
  const int tq = lane >> 4, tr = lane & 15, tr7 = tr & 7;
  const int rsub = lane >> 3;
  const int csw = ((lane & 7) ^ rsub) * 8;  // pre-swizzled GLOBAL source elems
                                            // (LDS dest stays linear: DMA rule)

  const __bf16* wlo = wT + (size_t)elo * HDIM * DDIM + (size_t)(gx * 128) * DDIM;
  const __bf16* whi = wT + (size_t)ehi * HDIM * DDIM + (size_t)(gx * 128) * DDIM;
  const __bf16* aptr[4];
  const __bf16* lptr[4];
  const __bf16* hptr[4];
#pragma unroll
  for (int it = 0; it < 4; ++it) {
    int r = it * 32 + w * 8 + rsub;
    aptr[it] = xb + (size_t)tok_s[r] * DDIM + csw;
    lptr[it] = wlo + (size_t)r * DDIM + csw;
    hptr[it] = whi + (size_t)r * DDIM + csw;
  }

  for (int kk = 0; kk < 16; ++kk) {
#pragma unroll
    for (int it = 0; it < 4; ++it) {
      const int rb = it * 32 + w * 8;
      cp16((char*)Ash  + rb * 128, aptr[it]); aptr[it] += 64;
      cp16((char*)BloS + rb * 128, lptr[it]); lptr[it] += 64;
      cp16((char*)BhiS + rb * 128, hptr[it]); hptr[it] += 64;
    }
    __syncthreads();
#pragma unroll
    for (int h = 0; h < 2; ++h) {
      const int co = (h << 2) | tq;
      bf16x8 a[4], bl[4], bh[4];
#pragma unroll
      for (int mi = 0; mi < 4; ++mi)
        a[mi] = *(const bf16x8*)((const char*)Ash + (wm + mi * 16 + tr) * 128 +
                                 ((co ^ tr7) << 4));
#pragma unroll
      for (int ni = 0; ni < 4; ++ni) {
        bl[ni] = *(const bf16x8*)((const char*)BloS + (wn + ni * 16 + tr) * 128 +
                                  ((co ^ tr7) << 4));
        bh[ni] = *(const bf16x8*)((const char*)BhiS + (wn + ni * 16 + tr) * 128 +
                                  ((co ^ tr7) << 4));
      }
#pragma unroll
      for (int mi = 0; mi < 4; ++mi)
#pragma unroll
        for (int ni = 0; ni < 4; ++ni) {
          accL[mi][ni] = __builtin_amdgcn_mfma_f32_16x16x32_bf16(a[mi], bl[ni], accL[mi][ni], 0, 0, 0);
          accH[mi][ni] = __builtin_amdgcn_mfma_f32_16x16x32_bf16(a[mi], bh[ni], accH[mi][ni], 0, 0, 0);
        }
    }
    __syncthreads();
  }

  // epilogue: out = plo*(accL + b_lo) + phi*(accH + b_hi), single plain store
  float blov[4], bhiv[4];
#pragma unroll
  for (int ni = 0; ni < 4; ++ni) {
    int col = gx * 128 + wn + ni * 16 + tr;
    blov[ni] = eb[elo * HDIM + col];
    bhiv[ni] = eb[ehi * HDIM + col];
  }
#pragma unroll
  for (int mi = 0; mi < 4; ++mi)
#pragma unroll
    for (int r = 0; r < 4; ++r) {
      int lr = wm + mi * 16 + tq * 4 + r;
      if (row0 + lr < cntp) {
        int    tok = tok_s[lr];
        float2 pp  = pp_s[lr];
        float* orow = out + (size_t)tok * HDIM + gx * 128 + wn + tr;
#pragma unroll
        for (int ni = 0; ni < 4; ++ni)
          orow[ni * 16] = pp.x * (accL[mi][ni][r] + blov[ni]) +
                          pp.y * (accH[mi][ni][r] + bhiv[ni]);
      }
    }
}

extern "C" void kernel_launch(void* const* d_in, const int* in_sizes, int n_in,
                              void* d_out, int out_size, void* d_ws, size_t ws_size,
                              hipStream_t stream) {
  const float* x  = (const float*)d_in[0];
  const float* gw = (const float*)d_in[1];
  const float* gb = (const float*)d_in[2];
  const float* ew = (const float*)d_in[3];
  const float* eb = (const float*)d_in[4];
  float* out = (float*)d_out;
  char*  ws  = (char*)d_ws;

  __bf16* xb     = (__bf16*)(ws + XB_OFF);
  __bf16* wT     = (__bf16*)(ws + WT_OFF);
  int*    idx_p  = (int*)(ws + IDXP_OFF);
  float2* pp_p   = (float2*)(ws + PPP_OFF);
  int*    tt_pid = (int*)(ws + TPID_OFF);
  float2* tt_pp  = (float2*)(ws + TPP_OFF);
  unsigned char* cnt_blk = (unsigned char*)(ws + CNTB_OFF);
  float*  ent_blk = (float*)(ws + ENTB_OFF);
  int*    tot_g   = (int*)(ws + TOT_OFF);

  prep_kernel<<<dim3(3072), 256, 0, stream>>>(ew, wT, x, gw, gb, xb,
                                              tt_pid, tt_pp, cnt_blk, ent_blk);
  scatter_kernel<<<dim3(64), 256, 0, stream>>>(tt_pid, tt_pp, cnt_blk, ent_blk,
                                               idx_p, pp_p, tot_g,
                                               out + (size_t)NTOK * HDIM);
  moe_gemm<<<dim3(8, 160), 256, 0, stream>>>(xb, wT, eb, idx_p, pp_p, tot_g,
                                             out);
}

// Round 7
// 310.582 us; speedup vs baseline: 1.0665x; 1.0665x over previous
//
#include <hip/hip_runtime.h>
#include <hip/hip_bf16.h>

typedef __bf16 bf16x8 __attribute__((ext_vector_type(8)));
typedef __bf16 bf16x4 __attribute__((ext_vector_type(4)));
typedef float  f32x4  __attribute__((ext_vector_type(4)));

#define NTOK 16384
#define DDIM 1024
#define HDIM 1024

// workspace layout (bytes)
#define XB_OFF   0u          // bf16 x        [NTOK][DDIM]     33,554,432
#define WT_OFF   33554432u   // bf16 W^T      [E][H][D]        16,777,216
#define IDXP_OFF 50331648u   // int   idx_packed [NTOK]            65,536
#define PPP_OFF  50397184u   // f32x2 pp_packed  [NTOK]           131,072
#define TPID_OFF 50528256u   // int   tt_pid [NTOK]                65,536
#define TPP_OFF  50593792u   // f32x2 tt_pp  [NTOK]               131,072
#define CNTB_OFF 50724864u   // u8  cnt_blk [1024][64]             65,536
#define ENTB_OFF 50790400u   // f32 ent_blk [1024]                  4,096
#define TOT_OFF  50794496u   // int tot [64]                          256

typedef __attribute__((address_space(1))) void gvoid_t;
typedef __attribute__((address_space(3))) void lvoid_t;

__device__ __forceinline__ void cp16(void* lds, const void* g) {
  __builtin_amdgcn_global_load_lds((gvoid_t*)g, (lvoid_t*)lds, 16, 0, 0);
}

// ============ K1: fused  transpose_w (blocks 0..2047)  +  gate (2048..3071) ====
// One dispatch instead of two (independent producers). Gate emits PER-BLOCK
// count bytes + per-block entropy with plain stores -> no zeroed global memory
// anywhere in the pipeline, no global atomics.
__global__ __launch_bounds__(256) void prep_kernel(
    const float* __restrict__ ew, __bf16* __restrict__ wT,
    const float* __restrict__ x, const float* __restrict__ gw,
    const float* __restrict__ gb, __bf16* __restrict__ xb,
    int* __restrict__ tt_pid, float2* __restrict__ tt_pp,
    unsigned char* __restrict__ cnt_blk, float* __restrict__ ent_blk) {
  __shared__ __align__(16) char smem[33040];
  const int tid = threadIdx.x;

  if (blockIdx.x < 2048) {
    // ---- transpose path: expert_w [E][D][H] f32 -> W^T [E][H][D] bf16 ----
    typedef float (*TileT)[69];
    TileT tile = (TileT)smem;
    const int b  = blockIdx.x;
    const int e  = b >> 8;
    const int d0 = ((b >> 4) & 15) * 64;
    const int h0 = (b & 15) * 64;
    const float* base = ew + ((size_t)e * DDIM + d0) * HDIM + h0;
#pragma unroll
    for (int it = 0; it < 4; ++it) {
      int dl = it * 16 + (tid >> 4);
      int hl = (tid & 15) * 4;
      float4 v = *(const float4*)(base + (size_t)dl * HDIM + hl);
      tile[dl][hl]     = v.x;
      tile[dl][hl + 1] = v.y;
      tile[dl][hl + 2] = v.z;
      tile[dl][hl + 3] = v.w;
    }
    __syncthreads();
    __bf16* obase = wT + ((size_t)e * HDIM + h0) * DDIM + d0;
#pragma unroll
    for (int it = 0; it < 2; ++it) {
      int hl = it * 32 + (tid >> 3);   // h row 0..63
      int dl = (tid & 7) * 8;          // 16B chunk of the 128B d-row
      bf16x8 bv;
#pragma unroll
      for (int i = 0; i < 8; ++i) bv[i] = (__bf16)tile[dl + i][hl];
      *(bf16x8*)(obase + (size_t)hl * DDIM + dl) = bv;
    }
    return;
  }

  // ---- gate path: logits/softmax/entropy/top2 -> pid+probs, x->bf16 ----
  float* gwT  = (float*)smem;            // 8*1024 f32 = 32768 B
  int*   lcnt = (int*)(smem + 32768);    // 64 ints
  float* went = (float*)(smem + 33024);  // 4 f32
  const int bid = blockIdx.x - 2048;
  const int wv = tid >> 6, lane = tid & 63;
  for (int i = tid; i < 64; i += 256) lcnt[i] = 0;
#pragma unroll
  for (int i = 0; i < 32; ++i) {  // gate_w [D][8] -> gwT [8][1024]
    int lin = i * 256 + tid;
    gwT[(lin & 7) * 1024 + (lin >> 3)] = gw[lin];
  }
  __syncthreads();
  float4 gr[4][8];
#pragma unroll
  for (int j = 0; j < 4; ++j)
#pragma unroll
    for (int e = 0; e < 8; ++e)
      gr[j][e] = *(const float4*)&gwT[e * 1024 + j * 256 + lane * 4];
  float gbr[8];
#pragma unroll
  for (int e = 0; e < 8; ++e) gbr[e] = gb[e];

  float entacc = 0.f;
  for (int t = 0; t < 4; ++t) {
    const int n = bid * 16 + wv * 4 + t;
    float acc[8] = {0.f, 0.f, 0.f, 0.f, 0.f, 0.f, 0.f, 0.f};
#pragma unroll
    for (int j = 0; j < 4; ++j) {
      float4 v = *(const float4*)(x + (size_t)n * DDIM + j * 256 + lane * 4);
      bf16x4 bv;
      bv[0] = (__bf16)v.x; bv[1] = (__bf16)v.y;
      bv[2] = (__bf16)v.z; bv[3] = (__bf16)v.w;
      *(bf16x4*)(xb + (size_t)n * DDIM + j * 256 + lane * 4) = bv;
#pragma unroll
      for (int e = 0; e < 8; ++e) {
        float4 g = gr[j][e];
        acc[e] += v.x * g.x + v.y * g.y + v.z * g.z + v.w * g.w;
      }
    }
#pragma unroll
    for (int e = 0; e < 8; ++e) {
      float s = acc[e];
#pragma unroll
      for (int off = 1; off < 64; off <<= 1) s += __shfl_xor(s, off);
      acc[e] = s;
    }
    // softmax + entropy via log-identity: ent = log(s) - sum p*(l-mx)
    float p[8], lg[8];
    float mx = -1e30f;
#pragma unroll
    for (int e = 0; e < 8; ++e) { p[e] = acc[e] + gbr[e]; mx = fmaxf(mx, p[e]); }
    float s = 0.f;
#pragma unroll
    for (int e = 0; e < 8; ++e) { lg[e] = p[e] - mx; p[e] = expf(lg[e]); s += p[e]; }
    float inv = 1.0f / s;
    float dot = 0.f;
#pragma unroll
    for (int e = 0; e < 8; ++e) { p[e] *= inv; dot += p[e] * lg[e]; }
    entacc += logf(s) - dot;
    int e1 = 0; float p1 = p[0];
#pragma unroll
    for (int e = 1; e < 8; ++e) if (p[e] > p1) { p1 = p[e]; e1 = e; }
    int e2 = (e1 == 0) ? 1 : 0; float p2 = p[e2];
#pragma unroll
    for (int e = 0; e < 8; ++e) if (e != e1 && p[e] > p2) { p2 = p[e]; e2 = e; }
    int   elo = (e1 < e2) ? e1 : e2;
    int   ehi = (e1 < e2) ? e2 : e1;
    float plo = (e1 < e2) ? p1 : p2;
    float phi = (e1 < e2) ? p2 : p1;
    int pid = elo * 8 + ehi;
    if (lane == 0) {
      tt_pid[n] = pid;
      tt_pp[n]  = make_float2(plo, phi);
      atomicAdd(&lcnt[pid], 1);
    }
  }
  if (lane == 0) went[wv] = entacc;
  __syncthreads();
  if (tid < 64) cnt_blk[bid * 64 + tid] = (unsigned char)lcnt[tid];
  if (tid == 0) ent_blk[bid] = went[0] + went[1] + went[2] + went[3];
}

// ============ K2: scatter (computes bases itself; block 0 does loss) ==========
// Each block column-reduces cnt_blk[1024][64] into totals + its own
// cross-block offsets (deterministic, no global atomics). Scatter block b owns
// gate blocks [16b,16b+16) -> offset counts gate blocks bb < 16*b.
__global__ __launch_bounds__(256) void scatter_kernel(
    const int* __restrict__ tt_pid, const float2* __restrict__ tt_pp,
    const unsigned char* __restrict__ cnt_blk, const float* __restrict__ ent_blk,
    int* __restrict__ idx_p, float2* __restrict__ pp_p,
    int* __restrict__ tot_g, float* __restrict__ loss_out) {
  __shared__ int part_tot[4][64], part_off[4][64];
  __shared__ int tot_l[64], off_l[64], base_l[64], lcnt[64];
  __shared__ float esum[4];
  const int t = threadIdx.x, b = blockIdx.x;
  const int p = t & 63, q = t >> 6;
  const int bcut = b * 16;   // first gate block owned by this scatter block

  int s_tot = 0, s_off = 0;
  for (int i = 0; i < 256; ++i) {
    int bb = q * 256 + i;
    int c = cnt_blk[bb * 64 + p];   // 64 lanes hit one 64B line per iter
    s_tot += c;
    s_off += (bb < bcut) ? c : 0;
  }
  part_tot[q][p] = s_tot;
  part_off[q][p] = s_off;
  if (t < 64) lcnt[t] = 0;
  __syncthreads();
  if (t < 64) {
    tot_l[t] = part_tot[0][t] + part_tot[1][t] + part_tot[2][t] + part_tot[3][t];
    off_l[t] = part_off[0][t] + part_off[1][t] + part_off[2][t] + part_off[3][t];
  }
  __syncthreads();
  if (t < 64) {
    int base = 0;
    for (int i = 0; i < t; ++i) base += tot_l[i];
    base_l[t] = base;
  }
  const int n   = b * 256 + t;
  const int pid = tt_pid[n];
  const float2 pp = tt_pp[n];
  __syncthreads();
  int lofs = atomicAdd(&lcnt[pid], 1);   // within-segment order arbitrary (ok)
  int dst = base_l[pid] + off_l[pid] + lofs;
  idx_p[dst] = n;
  pp_p[dst]  = pp;

  if (b == 0) {
    if (t < 64) tot_g[t] = tot_l[t];
    // entropy reduce: 1024 floats
    float e = ent_blk[t] + ent_blk[t + 256] + ent_blk[t + 512] + ent_blk[t + 768];
#pragma unroll
    for (int off = 1; off < 64; off <<= 1) e += __shfl_xor(e, off);
    if ((t & 63) == 0) esum[t >> 6] = e;
    __syncthreads();
    if (t == 0) {
      float ent = esum[0] + esum[1] + esum[2] + esum[3];
      int ecnt[8] = {0, 0, 0, 0, 0, 0, 0, 0};
      for (int pd = 0; pd < 64; ++pd) {
        int c = tot_l[pd];
        ecnt[pd >> 3] += c;
        ecnt[pd & 7]  += c;
      }
      float pen = 0.f;
      for (int e8 = 0; e8 < 8; ++e8) {
        float r = (float)ecnt[e8] / (float)NTOK - 0.3f;
        if (r > 0.f) pen += r;
      }
      loss_out[0] = 0.1f * (ent / (float)NTOK) + pen;
    }
  }
}

// ============ K3: pair-grouped dual-expert GEMM ==============================
// R6a: descriptor via 64-lane shuffle prefix-scan + ballot (replaces R5's
//      thread-0 serial walk = 64 dependent ~120cy ds_reads ~3us/block with all
//      4 waves parked at the barrier -- the R3->R5 regression).
// R6b: BK=32 double-buffer, 2-phase pipeline at CONSTANT LDS (2x24KB=48KB ~=
//      old 49.5KB -> 3 blocks/CU TLP preserved, unlike R2's 99KB which lost
//      it). Next K-slice's 6 DMA loads issue BEFORE compute; the single
//      end-of-step __syncthreads drains them after a full compute phase in
//      flight. Swizzle: 4 chunks/row XOR row&3, linear DMA dest +
//      pre-swizzled source + swizzled read (both-sides rule).
__global__ __launch_bounds__(256) void moe_gemm(
    const __bf16* __restrict__ xb, const __bf16* __restrict__ wT,
    const float* __restrict__ eb, const int* __restrict__ idx_p,
    const float2* __restrict__ pp_p, const int* __restrict__ tot_g,
    float* __restrict__ out) {
  const int gy = blockIdx.y, gx = blockIdx.x;
  const int tid = threadIdx.x, w = tid >> 6, lane = tid & 63;

  // ---- parallel tile descriptor: lane pd holds pair pd's count ----
  int c_pd = tot_g[lane];
  int ntl  = (c_pd + 127) >> 7;
  int cinc = c_pd, tinc = ntl;
#pragma unroll
  for (int off = 1; off < 64; off <<= 1) {
    int vc = __shfl_up(cinc, off);
    int vt = __shfl_up(tinc, off);
    if (lane >= off) { cinc += vc; tinc += vt; }
  }
  const int cexc = cinc - c_pd;   // tokens before this pid
  const int texc = tinc - ntl;    // tiles before this pid
  bool own = (c_pd > 0) && (gy >= texc) && (gy < texc + ntl);
  unsigned long long mask = __ballot(own);
  if (mask == 0ull) return;       // gy beyond last tile
  const int src  = (int)__builtin_ctzll(mask);
  const int pid  = src;
  const int cntp = __shfl(c_pd, src);
  const int gbase = __shfl(cexc, src);
  const int row0  = (gy - __shfl(texc, src)) * 128;
  const int elo = pid >> 3, ehi = pid & 7;

  __shared__ __bf16 Abuf[2][128 * 32];
  __shared__ __bf16 Lbuf[2][128 * 32];
  __shared__ __bf16 Hbuf[2][128 * 32];
  __shared__ int    tok_s[128];
  __shared__ float2 pp_s[128];

  if (tid < 128) {
    int s = row0 + tid;
    int g = gbase + ((s < cntp) ? s : (cntp - 1));
    tok_s[tid] = idx_p[g];
    pp_s[tid]  = pp_p[g];
  }
  __syncthreads();

  f32x4 accL[4][4], accH[4][4];
  const f32x4 zero = {0.f, 0.f, 0.f, 0.f};
#pragma unroll
  for (int mi = 0; mi < 4; ++mi)
#pragma unroll
    for (int ni = 0; ni < 4; ++ni) { accL[mi][ni] = zero; accH[mi][ni] = zero; }

  const int wm = (w >> 1) * 64, wn = (w & 1) * 64;
  const int tq = lane >> 4, tr = lane & 15;
  // staging decomposition: lane = rloc*4 + cg; rows 16/wave-chunk, 4x16B chunks
  const int rloc = lane >> 2;            // row within 16-row chunk
  const int cg   = lane & 3;             // linear LDS chunk (DMA dest)
  const int scol = (cg ^ (rloc & 3)) * 8;  // pre-swizzled global col (elems)

  const __bf16* wlo = wT + (size_t)elo * HDIM * DDIM + (size_t)(gx * 128) * DDIM;
  const __bf16* whi = wT + (size_t)ehi * HDIM * DDIM + (size_t)(gx * 128) * DDIM;
  const __bf16* aptr[2];
  const __bf16* lptr[2];
  const __bf16* hptr[2];
  int dofs[2];
#pragma unroll
  for (int i = 0; i < 2; ++i) {
    int r = (i * 4 + w) * 16 + rloc;     // 0..127
    aptr[i] = xb + (size_t)tok_s[r] * DDIM + scol;
    lptr[i] = wlo + (size_t)r * DDIM + scol;
    hptr[i] = whi + (size_t)r * DDIM + scol;
    dofs[i] = (i * 4 + w) * 1024;        // wave-uniform byte offset (HW adds lane*16)
  }

  // prologue: stage K-slice 0 into buffer 0
#pragma unroll
  for (int i = 0; i < 2; ++i) {
    cp16((char*)Abuf[0] + dofs[i], aptr[i]); aptr[i] += 32;
    cp16((char*)Lbuf[0] + dofs[i], lptr[i]); lptr[i] += 32;
    cp16((char*)Hbuf[0] + dofs[i], hptr[i]); hptr[i] += 32;
  }
  __syncthreads();

  const int chq = (tq ^ (tr & 3)) << 4;  // swizzled read chunk (bytes)
  int bsel = 0;
  for (int kk = 0; kk < 32; ++kk) {
    // issue next slice's DMA first: in flight under this slice's compute
    if (kk < 31) {
#pragma unroll
      for (int i = 0; i < 2; ++i) {
        cp16((char*)Abuf[bsel ^ 1] + dofs[i], aptr[i]); aptr[i] += 32;
        cp16((char*)Lbuf[bsel ^ 1] + dofs[i], lptr[i]); lptr[i] += 32;
        cp16((char*)Hbuf[bsel ^ 1] + dofs[i], hptr[i]); hptr[i] += 32;
      }
    }
    bf16x8 a[4], bl[4], bh[4];
#pragma unroll
    for (int mi = 0; mi < 4; ++mi)
      a[mi] = *(const bf16x8*)((const char*)Abuf[bsel] + (wm + mi * 16 + tr) * 64 + chq);
#pragma unroll
    for (int ni = 0; ni < 4; ++ni) {
      bl[ni] = *(const bf16x8*)((const char*)Lbuf[bsel] + (wn + ni * 16 + tr) * 64 + chq);
      bh[ni] = *(const bf16x8*)((const char*)Hbuf[bsel] + (wn + ni * 16 + tr) * 64 + chq);
    }
#pragma unroll
    for (int mi = 0; mi < 4; ++mi)
#pragma unroll
      for (int ni = 0; ni < 4; ++ni) {
        accL[mi][ni] = __builtin_amdgcn_mfma_f32_16x16x32_bf16(a[mi], bl[ni], accL[mi][ni], 0, 0, 0);
        accH[mi][ni] = __builtin_amdgcn_mfma_f32_16x16x32_bf16(a[mi], bh[ni], accH[mi][ni], 0, 0, 0);
      }
    // one barrier/step: vmcnt(0) covers slice kk+1 (issued a compute-phase
    // ago) and the barrier resolves the WAR on buffer bsel for step kk+1.
    if (kk < 31) { __syncthreads(); bsel ^= 1; }
  }

  // epilogue: out = plo*(accL + b_lo) + phi*(accH + b_hi), single plain store
  float blov[4], bhiv[4];
#pragma unroll
  for (int ni = 0; ni < 4; ++ni) {
    int col = gx * 128 + wn + ni * 16 + tr;
    blov[ni] = eb[elo * HDIM + col];
    bhiv[ni] = eb[ehi * HDIM + col];
  }
#pragma unroll
  for (int mi = 0; mi < 4; ++mi)
#pragma unroll
    for (int r = 0; r < 4; ++r) {
      int lr = wm + mi * 16 + tq * 4 + r;
      if (row0 + lr < cntp) {
        int    tok = tok_s[lr];
        float2 pp  = pp_s[lr];
        float* orow = out + (size_t)tok * HDIM + gx * 128 + wn + tr;
#pragma unroll
        for (int ni = 0; ni < 4; ++ni)
          orow[ni * 16] = pp.x * (accL[mi][ni][r] + blov[ni]) +
                          pp.y * (accH[mi][ni][r] + bhiv[ni]);
      }
    }
}

extern "C" void kernel_launch(void* const* d_in, const int* in_sizes, int n_in,
                              void* d_out, int out_size, void* d_ws, size_t ws_size,
                              hipStream_t stream) {
  const float* x  = (const float*)d_in[0];
  const float* gw = (const float*)d_in[1];
  const float* gb = (const float*)d_in[2];
  const float* ew = (const float*)d_in[3];
  const float* eb = (const float*)d_in[4];
  float* out = (float*)d_out;
  char*  ws  = (char*)d_ws;

  __bf16* xb     = (__bf16*)(ws + XB_OFF);
  __bf16* wT     = (__bf16*)(ws + WT_OFF);
  int*    idx_p  = (int*)(ws + IDXP_OFF);
  float2* pp_p   = (float2*)(ws + PPP_OFF);
  int*    tt_pid = (int*)(ws + TPID_OFF);
  float2* tt_pp  = (float2*)(ws + TPP_OFF);
  unsigned char* cnt_blk = (unsigned char*)(ws + CNTB_OFF);
  float*  ent_blk = (float*)(ws + ENTB_OFF);
  int*    tot_g   = (int*)(ws + TOT_OFF);

  prep_kernel<<<dim3(3072), 256, 0, stream>>>(ew, wT, x, gw, gb, xb,
                                              tt_pid, tt_pp, cnt_blk, ent_blk);
  scatter_kernel<<<dim3(64), 256, 0, stream>>>(tt_pid, tt_pp, cnt_blk, ent_blk,
                                               idx_p, pp_p, tot_g,
                                               out + (size_t)NTOK * HDIM);
  moe_gemm<<<dim3(8, 160), 256, 0, stream>>>(xb, wT, eb, idx_p, pp_p, tot_g,
                                             out);
}